// Round 2
// baseline (8855.585 us; speedup 1.0000x reference)
//
#include <hip/hip_runtime.h>

typedef _Float16 f16;
typedef _Float16 f16x8 __attribute__((ext_vector_type(8)));
typedef float    f32x16 __attribute__((ext_vector_type(16)));

#define T_STEPS 512
#define RING    16   // ring depth (power of 2), slots of 128x512 f16

// ---------------- helpers ----------------

__device__ __forceinline__ void gload_lds16(const void* g, void* l) {
  // async global->LDS, 16B per lane; LDS dest = base + lane*16 (linear)
  __builtin_amdgcn_global_load_lds((const __attribute__((address_space(1))) void*)g,
                                   (__attribute__((address_space(3))) void*)l,
                                   16, 0, 0);
}

__device__ __forceinline__ float sigm(float x) { return 1.0f / (1.0f + __expf(-x)); }
__device__ __forceinline__ float tanh_f(float x) { return 2.0f / (1.0f + __expf(-2.0f * x)) - 1.0f; }

// returns false on timeout (safety valve: avoids multi-minute hangs if a block
// failed to become resident; results will then be wrong but bench returns)
__device__ __forceinline__ bool spin_until(int* p, int target) {
  int it = 0;
  while (__hip_atomic_load(p, __ATOMIC_RELAXED, __HIP_MEMORY_SCOPE_AGENT) < target) {
    __builtin_amdgcn_s_sleep(1);
    if (++it > (1 << 20)) return false;
  }
  return true;
}

// ---------------- fp32 -> fp16 convert (input_seq) ----------------

__global__ void cvt_kernel(const float* __restrict__ in, f16* __restrict__ out, int n8) {
  int i = blockIdx.x * blockDim.x + threadIdx.x;
  if (i >= n8) return;
  const float4* p = (const float4*)in + (size_t)i * 2;
  float4 a = p[0], b = p[1];
  f16x8 v = {(f16)a.x, (f16)a.y, (f16)a.z, (f16)a.w,
             (f16)b.x, (f16)b.y, (f16)b.z, (f16)b.w};
  *((f16x8*)out + i) = v;
}

// ---------------- persistent 2-layer LSTM scan ----------------
//
// 256 blocks x 256 threads, 1 block/CU (82KB LDS forces this -> co-resident).
// bid: xcd=bid&7 -> layer=xcd&1, batch-group g=xcd>>1 (32 rows each); j=bid>>3
// Block (layer,g,j) owns h cols [16j,16j+16) i.e. gate cols q*512+16j.. for q=0..3.
// Wave w (of 4): n-tile nt=w&1 (nt0: gates i,f; nt1: gates g,o), K-half kh=w>>1.
// Each wave holds its B (weights) as 32x f16x8 fragments in VGPRs for the whole scan.
// A (32 x 1024 = [x_part ; h_part]) staged to LDS fragment-major per step.
// Sync: monotonic counters cnt[t][g] per layer; relaxed spin + one threadfence.

__launch_bounds__(256, 1)
__global__ void lstm_scan(const f16* __restrict__ X16,
                          f16* __restrict__ h1ring, f16* __restrict__ h2ring,
                          int* __restrict__ cnt1, int* __restrict__ cnt2,
                          const float* __restrict__ Wih0, const float* __restrict__ Whh0,
                          const float* __restrict__ bih0, const float* __restrict__ bhh0,
                          const float* __restrict__ Wih1, const float* __restrict__ Whh1,
                          const float* __restrict__ bih1, const float* __restrict__ bhh1,
                          float* __restrict__ out) {
  __shared__ __align__(16) char A_lds[65536];   // [64 ksteps][kgrp][row][8 f16]
  __shared__ float P[2][32][32];                // kh=1 partial acc
  __shared__ float G[2][32][32];                // full gate preacts (no bias)
  __shared__ float bias_lds[64];
  __shared__ float c_lds[512];                  // cell state, 32 rows x 16 cols

  const int bid  = blockIdx.x;
  const int xcd  = bid & 7;
  const int layer = xcd & 1;
  const int g    = xcd >> 1;
  const int j    = bid >> 3;
  const int tid  = threadIdx.x;
  const int w    = tid >> 6;
  const int lane = tid & 63;
  const int c32  = lane & 31;
  const int kgrp = lane >> 5;
  const int nt   = w & 1;
  const int kh   = w >> 1;

  // ---- load weights into registers (one-time) ----
  // tile col c32 -> gate q, global gate-col wcol; B-frag: lane holds W[wcol][k..k+8]
  const float* Wsrc = layer ? (kh ? Whh1 : Wih1) : (kh ? Whh0 : Wih0);
  const int q    = nt * 2 + (c32 >> 4);
  const int wcol = q * 512 + j * 16 + (c32 & 15);
  f16x8 wreg[32];
  {
    const float* wrow = Wsrc + (size_t)wcol * 512 + kgrp * 8;
#pragma unroll
    for (int s = 0; s < 32; ++s) {
      const float* p = wrow + s * 16;
      float4 a = *(const float4*)p;
      float4 b = *(const float4*)(p + 4);
      f16x8 v = {(f16)a.x, (f16)a.y, (f16)a.z, (f16)a.w,
                 (f16)b.x, (f16)b.y, (f16)b.z, (f16)b.w};
      wreg[s] = v;
    }
  }
  if (tid < 64) {
    int c = tid & 31, n = tid >> 5;
    int qq  = n * 2 + (c >> 4);
    int col = qq * 512 + j * 16 + (c & 15);
    bias_lds[tid] = layer ? (bih1[col] + bhh1[col]) : (bih0[col] + bhh0[col]);
  }
  for (int e = tid; e < 512; e += 256) c_lds[e] = 0.0f;
  __syncthreads();

  int* cntOwn = layer ? cnt2 : cnt1;
  const int b_stage = g * 32 + c32;   // batch row this lane stages

  bool alive = true;
  for (int t = 0; t < T_STEPS; ++t) {
    // ---- wait for dependencies ----
    if (tid == 0) {
      if (alive) {
        if (layer == 0) {
          if (t > 0)     alive &= spin_until(&cnt1[(t - 1) * 4 + g], 32);
          if (t >= RING) alive &= spin_until(&cnt2[(t - RING) * 4 + g], 32);  // ring anti-dep
        } else {
          alive &= spin_until(&cnt1[t * 4 + g], 32);
          if (t > 0) alive &= spin_until(&cnt2[(t - 1) * 4 + g], 32);
        }
      }
      __threadfence();   // acquire: invalidate L1/L2 so fresh h is visible
    }
    __syncthreads();

    // ---- stage A = [part0(k<512) ; part1(k>=512)] fragment-major into LDS ----
    // waves 0,1 stage part0 (X_t for L0 / h1[t] for L1); waves 2,3 stage part1 (h ring)
    {
      const f16* part0 = layer ? (h1ring + (size_t)((t + 1) & (RING - 1)) * 65536)
                               : (X16 + (size_t)t * 65536);
      const f16* part1 = layer ? (h2ring + (size_t)(t & (RING - 1)) * 65536)
                               : (h1ring + (size_t)(t & (RING - 1)) * 65536);
      const f16* base = (w < 2) ? part0 : part1;
      const f16* lsrc = base + (size_t)b_stage * 512 + (w & 1) * 256 + kgrp * 8;
      char* ldst = A_lds + w * 16 * 1024;
#pragma unroll
      for (int si = 0; si < 16; ++si) {
        gload_lds16(lsrc + si * 16, ldst + si * 1024);
      }
    }
    __syncthreads();

    // ---- MFMA: acc(32x32) over this wave's K-half, B from registers ----
    f32x16 acc0 = {}, acc1 = {}, acc2 = {}, acc3 = {};
    {
      const char* afb = A_lds + kh * 32768 + kgrp * 512 + c32 * 16;
#pragma unroll
      for (int s = 0; s < 32; s += 4) {
        f16x8 a0 = *(const f16x8*)(afb + (size_t)(s + 0) * 1024);
        f16x8 a1 = *(const f16x8*)(afb + (size_t)(s + 1) * 1024);
        f16x8 a2 = *(const f16x8*)(afb + (size_t)(s + 2) * 1024);
        f16x8 a3 = *(const f16x8*)(afb + (size_t)(s + 3) * 1024);
        acc0 = __builtin_amdgcn_mfma_f32_32x32x16_f16(a0, wreg[s + 0], acc0, 0, 0, 0);
        acc1 = __builtin_amdgcn_mfma_f32_32x32x16_f16(a1, wreg[s + 1], acc1, 0, 0, 0);
        acc2 = __builtin_amdgcn_mfma_f32_32x32x16_f16(a2, wreg[s + 2], acc2, 0, 0, 0);
        acc3 = __builtin_amdgcn_mfma_f32_32x32x16_f16(a3, wreg[s + 3], acc3, 0, 0, 0);
      }
    }
    f32x16 accs = (acc0 + acc1) + (acc2 + acc3);

    // ---- combine K-halves: C layout col=lane&31, row=(i&3)+8*(i>>2)+4*(lane>>5) ----
    if (kh == 1) {
#pragma unroll
      for (int i = 0; i < 16; ++i) {
        int row = (i & 3) + 8 * (i >> 2) + 4 * kgrp;
        P[nt][row][c32] = accs[i];
      }
    }
    __syncthreads();
    if (kh == 0) {
#pragma unroll
      for (int i = 0; i < 16; ++i) {
        int row = (i & 3) + 8 * (i >> 2) + 4 * kgrp;
        G[nt][row][c32] = accs[i] + P[nt][row][c32];
      }
    }
    __syncthreads();

    // ---- elementwise LSTM cell update: 512 (row,col) pairs, 2 per thread ----
    {
      f16* ring = layer ? h2ring : h1ring;
      const size_t slot = (size_t)((t + 1) & (RING - 1)) * 65536;
#pragma unroll
      for (int u = 0; u < 2; ++u) {
        int e = tid * 2 + u;
        int r = e >> 4, cc = e & 15;
        float iv = G[0][r][cc]      + bias_lds[cc];
        float fv = G[0][r][cc + 16] + bias_lds[cc + 16];
        float gv = G[1][r][cc]      + bias_lds[32 + cc];
        float ov = G[1][r][cc + 16] + bias_lds[48 + cc];
        float c  = sigm(fv) * c_lds[e] + sigm(iv) * tanh_f(gv);
        c_lds[e] = c;
        float h  = sigm(ov) * tanh_f(c);
        ring[slot + (size_t)(g * 32 + r) * 512 + (j * 16 + cc)] = (f16)h;
        if (layer && t == T_STEPS - 1)
          out[(size_t)(g * 32 + r) * 512 + (j * 16 + cc)] = h;
      }
    }
    __syncthreads();   // all h stores drained (waitcnt before barrier)

    // ---- publish ----
    if (tid == 0) {
      __threadfence();                  // release: flush L2 so remote XCDs see h
      atomicAdd(&cntOwn[t * 4 + g], 1);
    }
  }
}

// ---------------- launch ----------------

extern "C" void kernel_launch(void* const* d_in, const int* in_sizes, int n_in,
                              void* d_out, int out_size, void* d_ws, size_t ws_size,
                              hipStream_t stream) {
  const float* X    = (const float*)d_in[0];
  const float* Wih0 = (const float*)d_in[1];
  const float* Whh0 = (const float*)d_in[2];
  const float* bih0 = (const float*)d_in[3];
  const float* bhh0 = (const float*)d_in[4];
  const float* Wih1 = (const float*)d_in[5];
  const float* Whh1 = (const float*)d_in[6];
  const float* bih1 = (const float*)d_in[7];
  const float* bhh1 = (const float*)d_in[8];
  float* out = (float*)d_out;

  char* ws = (char*)d_ws;
  size_t off = 0;
  f16* X16 = (f16*)(ws + off); off += (size_t)512 * 128 * 512 * 2;   // 64 MiB
  f16* h1r = (f16*)(ws + off); off += (size_t)RING * 128 * 512 * 2;  // 2 MiB
  f16* h2r = (f16*)(ws + off); off += (size_t)RING * 128 * 512 * 2;  // 2 MiB
  int* cnt1 = (int*)(ws + off); off += (size_t)512 * 4 * 4;
  int* cnt2 = (int*)(ws + off); off += (size_t)512 * 4 * 4;
  if (ws_size < off) return;  // insufficient workspace: fail visibly

  // zero counters and ring slot 0 (h[-1] = 0); d_ws is poisoned each call
  hipMemsetAsync(cnt1, 0, (size_t)512 * 4 * 4 * 2, stream);  // cnt1+cnt2 contiguous
  hipMemsetAsync(h1r, 0, (size_t)128 * 512 * 2, stream);
  hipMemsetAsync(h2r, 0, (size_t)128 * 512 * 2, stream);

  int n8 = (512 * 128 * 512) / 8;
  cvt_kernel<<<n8 / 256, 256, 0, stream>>>(X, X16, n8);
  lstm_scan<<<256, 256, 0, stream>>>(X16, h1r, h2r, cnt1, cnt2,
                                     Wih0, Whh0, bih0, bhh0,
                                     Wih1, Whh1, bih1, bhh1, out);
}

// Round 3
// 3682.640 us; speedup vs baseline: 2.4047x; 2.4047x over previous
//
#include <hip/hip_runtime.h>

typedef _Float16 f16;
typedef _Float16 f16x8 __attribute__((ext_vector_type(8)));
typedef float    f32x16 __attribute__((ext_vector_type(16)));

#define T_STEPS 512
#define RING    16   // ring depth (power of 2), slots of 128x512 f16

// ---------------- helpers ----------------

__device__ __forceinline__ void gload_lds16(const void* g, void* l) {
  // async global->LDS, 16B per lane; LDS dest = base + lane*16 (linear)
  __builtin_amdgcn_global_load_lds((const __attribute__((address_space(1))) void*)g,
                                   (__attribute__((address_space(3))) void*)l,
                                   16, 0, 0);
}

__device__ __forceinline__ float sigm(float x) { return 1.0f / (1.0f + __expf(-x)); }
__device__ __forceinline__ float tanh_f(float x) { return 2.0f / (1.0f + __expf(-2.0f * x)) - 1.0f; }

// returns false on timeout (safety valve: avoids multi-minute hangs if a block
// failed to become resident; results will then be wrong but bench returns)
__device__ __forceinline__ bool spin_until(int* p, int target) {
  int it = 0;
  while (__hip_atomic_load(p, __ATOMIC_RELAXED, __HIP_MEMORY_SCOPE_AGENT) < target) {
    __builtin_amdgcn_s_sleep(1);
    if (++it > (1 << 20)) return false;
  }
  return true;
}

// ---------------- fp32 -> fp16 convert (input_seq) ----------------

__global__ void cvt_kernel(const float* __restrict__ in, f16* __restrict__ out, int n8) {
  int i = blockIdx.x * blockDim.x + threadIdx.x;
  if (i >= n8) return;
  const float4* p = (const float4*)in + (size_t)i * 2;
  float4 a = p[0], b = p[1];
  f16x8 v = {(f16)a.x, (f16)a.y, (f16)a.z, (f16)a.w,
             (f16)b.x, (f16)b.y, (f16)b.z, (f16)b.w};
  *((f16x8*)out + i) = v;
}

// ---------------- persistent 2-layer LSTM scan ----------------
//
// 256 blocks x 256 threads, 1 block/CU (84KB LDS forces this -> co-resident).
// bid: xcd=bid&7 -> layer=xcd&1, batch-group g=xcd>>1 (32 rows each); j=bid>>3
// Block (layer,g,j) owns h cols [16j,16j+16) i.e. gate cols q*512+16j.. for q=0..3.
// Wave w (of 4): n-tile nt=w&1 (nt0: gates i,f; nt1: gates g,o), K-half kh=w>>1.
// Each wave holds its B (weights) as 32x f16x8 fragments in VGPRs for the whole scan.
// A (32 x 1024 = [x_part ; h_part]) staged to LDS fragment-major per step.
//
// Sync (r3): h published via CACHE-BYPASSING relaxed-agent stores (straight to
// LIC) -> NO release wbl2 fence. __syncthreads drains vmcnt before tid0's
// relaxed atomicAdd publish. Consumer: relaxed spin + acquire fence (inv only,
// no writeback) so ring-slot reuse can't hit stale L2. X_t staged BEFORE the
// spin (no dependency) to hide latency.

__launch_bounds__(256, 1)
__global__ void lstm_scan(const f16* __restrict__ X16,
                          f16* __restrict__ h1ring, f16* __restrict__ h2ring,
                          int* __restrict__ cnt1, int* __restrict__ cnt2,
                          const float* __restrict__ Wih0, const float* __restrict__ Whh0,
                          const float* __restrict__ bih0, const float* __restrict__ bhh0,
                          const float* __restrict__ Wih1, const float* __restrict__ Whh1,
                          const float* __restrict__ bih1, const float* __restrict__ bhh1,
                          float* __restrict__ out) {
  __shared__ __align__(16) char A_lds[65536];   // [64 ksteps][kgrp][row][8 f16]
  __shared__ float P[2][32][32];                // kh=1 partial acc
  __shared__ float G[2][32][32];                // full gate preacts (no bias)
  __shared__ float bias_lds[64];
  __shared__ float c_lds[512];                  // cell state, 32 rows x 16 cols

  const int bid  = blockIdx.x;
  const int xcd  = bid & 7;
  const int layer = xcd & 1;
  const int g    = xcd >> 1;
  const int j    = bid >> 3;
  const int tid  = threadIdx.x;
  const int w    = tid >> 6;
  const int lane = tid & 63;
  const int c32  = lane & 31;
  const int kgrp = lane >> 5;
  const int nt   = w & 1;
  const int kh   = w >> 1;

  // ---- load weights into registers (one-time) ----
  // tile col c32 -> gate q, global gate-col wcol; B-frag: lane holds W[wcol][k..k+8]
  const float* Wsrc = layer ? (kh ? Whh1 : Wih1) : (kh ? Whh0 : Wih0);
  const int q    = nt * 2 + (c32 >> 4);
  const int wcol = q * 512 + j * 16 + (c32 & 15);
  f16x8 wreg[32];
  {
    const float* wrow = Wsrc + (size_t)wcol * 512 + kgrp * 8;
#pragma unroll
    for (int s = 0; s < 32; ++s) {
      const float* p = wrow + s * 16;
      float4 a = *(const float4*)p;
      float4 b = *(const float4*)(p + 4);
      f16x8 v = {(f16)a.x, (f16)a.y, (f16)a.z, (f16)a.w,
                 (f16)b.x, (f16)b.y, (f16)b.z, (f16)b.w};
      wreg[s] = v;
    }
  }
  if (tid < 64) {
    int c = tid & 31, n = tid >> 5;
    int qq  = n * 2 + (c >> 4);
    int col = qq * 512 + j * 16 + (c & 15);
    bias_lds[tid] = layer ? (bih1[col] + bhh1[col]) : (bih0[col] + bhh0[col]);
  }
  for (int e = tid; e < 512; e += 256) c_lds[e] = 0.0f;
  __syncthreads();

  int* cntOwn = layer ? cnt2 : cnt1;
  const int b_stage = g * 32 + c32;   // batch row this lane stages

  bool alive = true;
  for (int t = 0; t < T_STEPS; ++t) {
    // ---- phase A: X prefetch (L0 waves 0,1) — independent of counters ----
    if (layer == 0 && w < 2) {
      const f16* base = X16 + (size_t)t * 65536;
      const f16* lsrc = base + (size_t)b_stage * 512 + nt * 256 + kgrp * 8;
      char* ldst = A_lds + w * 16384;
#pragma unroll
      for (int si = 0; si < 16; ++si) gload_lds16(lsrc + si * 16, ldst + si * 1024);
    }

    // ---- wait for dependencies; acquire = inv only (no writeback) ----
    if (tid == 0) {
      if (alive) {
        if (layer == 0) {
          if (t > 0)     alive &= spin_until(&cnt1[(t - 1) * 4 + g], 32);
          if (t >= RING) alive &= spin_until(&cnt2[(t - RING) * 4 + g], 32);  // ring anti-dep
        } else {
          alive &= spin_until(&cnt1[t * 4 + g], 32);
          if (t > 0) alive &= spin_until(&cnt2[(t - 1) * 4 + g], 32);
        }
      }
      __builtin_amdgcn_fence(__ATOMIC_ACQUIRE, "agent");   // buffer_inv, no wbl2
    }
    __syncthreads();

    // ---- phase B: stage h parts fragment-major into LDS ----
    {
      const f16* base = nullptr;
      if (layer == 0) {
        if (w >= 2) base = h1ring + (size_t)(t & (RING - 1)) * 65536;        // h1[t-1]
      } else {
        base = (w < 2) ? (h1ring + (size_t)((t + 1) & (RING - 1)) * 65536)   // h1[t]
                       : (h2ring + (size_t)(t & (RING - 1)) * 65536);        // h2[t-1]
      }
      if (base) {
        const f16* lsrc = base + (size_t)b_stage * 512 + nt * 256 + kgrp * 8;
        char* ldst = A_lds + w * 16384;
#pragma unroll
        for (int si = 0; si < 16; ++si) gload_lds16(lsrc + si * 16, ldst + si * 1024);
      }
    }
    __syncthreads();

    // ---- MFMA: acc(32x32) over this wave's K-half, B from registers ----
    f32x16 acc0 = {}, acc1 = {}, acc2 = {}, acc3 = {};
    {
      const char* afb = A_lds + kh * 32768 + kgrp * 512 + c32 * 16;
#pragma unroll
      for (int s = 0; s < 32; s += 4) {
        f16x8 a0 = *(const f16x8*)(afb + (size_t)(s + 0) * 1024);
        f16x8 a1 = *(const f16x8*)(afb + (size_t)(s + 1) * 1024);
        f16x8 a2 = *(const f16x8*)(afb + (size_t)(s + 2) * 1024);
        f16x8 a3 = *(const f16x8*)(afb + (size_t)(s + 3) * 1024);
        acc0 = __builtin_amdgcn_mfma_f32_32x32x16_f16(a0, wreg[s + 0], acc0, 0, 0, 0);
        acc1 = __builtin_amdgcn_mfma_f32_32x32x16_f16(a1, wreg[s + 1], acc1, 0, 0, 0);
        acc2 = __builtin_amdgcn_mfma_f32_32x32x16_f16(a2, wreg[s + 2], acc2, 0, 0, 0);
        acc3 = __builtin_amdgcn_mfma_f32_32x32x16_f16(a3, wreg[s + 3], acc3, 0, 0, 0);
      }
    }
    f32x16 accs = (acc0 + acc1) + (acc2 + acc3);

    // ---- combine K-halves: C layout col=lane&31, row=(i&3)+8*(i>>2)+4*(lane>>5) ----
    if (kh == 1) {
#pragma unroll
      for (int i = 0; i < 16; ++i) {
        int row = (i & 3) + 8 * (i >> 2) + 4 * kgrp;
        P[nt][row][c32] = accs[i];
      }
    }
    __syncthreads();
    if (kh == 0) {
#pragma unroll
      for (int i = 0; i < 16; ++i) {
        int row = (i & 3) + 8 * (i >> 2) + 4 * kgrp;
        G[nt][row][c32] = accs[i] + P[nt][row][c32];
      }
    }
    __syncthreads();

    // ---- elementwise LSTM cell update: 512 pairs, 2 per thread, packed 4B
    //      bypass store straight to LIC (no release fence needed) ----
    {
      f16* ring = layer ? h2ring : h1ring;
      const size_t slot = (size_t)((t + 1) & (RING - 1)) * 65536;
      const int e0 = tid * 2;
      const int r = e0 >> 4, cc = e0 & 15;   // cc even; cols cc, cc+1
      float hv[2];
#pragma unroll
      for (int u = 0; u < 2; ++u) {
        int cu = cc + u;
        float iv = G[0][r][cu]      + bias_lds[cu];
        float fv = G[0][r][cu + 16] + bias_lds[cu + 16];
        float gv = G[1][r][cu]      + bias_lds[32 + cu];
        float ov = G[1][r][cu + 16] + bias_lds[48 + cu];
        float c  = sigm(fv) * c_lds[e0 + u] + sigm(iv) * tanh_f(gv);
        c_lds[e0 + u] = c;
        hv[u] = sigm(ov) * tanh_f(c);
      }
      union { f16 h2_[2]; int i32; } pk;
      pk.h2_[0] = (f16)hv[0]; pk.h2_[1] = (f16)hv[1];
      int* dst = (int*)(ring + slot + (size_t)(g * 32 + r) * 512 + (j * 16 + cc));
      __hip_atomic_store(dst, pk.i32, __ATOMIC_RELAXED, __HIP_MEMORY_SCOPE_AGENT);
      if (layer && t == T_STEPS - 1) {
        out[(size_t)(g * 32 + r) * 512 + (j * 16 + cc)]     = hv[0];
        out[(size_t)(g * 32 + r) * 512 + (j * 16 + cc) + 1] = hv[1];
      }
    }
    __syncthreads();   // per-wave s_waitcnt vmcnt(0) before barrier: stores at LIC

    // ---- publish (relaxed; ordering provided by the barrier's vmcnt drain) ----
    if (tid == 0) {
      __hip_atomic_fetch_add(&cntOwn[t * 4 + g], 1,
                             __ATOMIC_RELAXED, __HIP_MEMORY_SCOPE_AGENT);
    }
  }
}

// ---------------- launch ----------------

extern "C" void kernel_launch(void* const* d_in, const int* in_sizes, int n_in,
                              void* d_out, int out_size, void* d_ws, size_t ws_size,
                              hipStream_t stream) {
  const float* X    = (const float*)d_in[0];
  const float* Wih0 = (const float*)d_in[1];
  const float* Whh0 = (const float*)d_in[2];
  const float* bih0 = (const float*)d_in[3];
  const float* bhh0 = (const float*)d_in[4];
  const float* Wih1 = (const float*)d_in[5];
  const float* Whh1 = (const float*)d_in[6];
  const float* bih1 = (const float*)d_in[7];
  const float* bhh1 = (const float*)d_in[8];
  float* out = (float*)d_out;

  char* ws = (char*)d_ws;
  size_t off = 0;
  f16* X16 = (f16*)(ws + off); off += (size_t)512 * 128 * 512 * 2;   // 64 MiB
  f16* h1r = (f16*)(ws + off); off += (size_t)RING * 128 * 512 * 2;  // 2 MiB
  f16* h2r = (f16*)(ws + off); off += (size_t)RING * 128 * 512 * 2;  // 2 MiB
  int* cnt1 = (int*)(ws + off); off += (size_t)512 * 4 * 4;
  int* cnt2 = (int*)(ws + off); off += (size_t)512 * 4 * 4;
  if (ws_size < off) return;  // insufficient workspace: fail visibly

  // zero counters and ring slot 0 (h[-1] = 0); d_ws is poisoned each call
  hipMemsetAsync(cnt1, 0, (size_t)512 * 4 * 4 * 2, stream);  // cnt1+cnt2 contiguous
  hipMemsetAsync(h1r, 0, (size_t)128 * 512 * 2, stream);
  hipMemsetAsync(h2r, 0, (size_t)128 * 512 * 2, stream);

  int n8 = (512 * 128 * 512) / 8;
  cvt_kernel<<<n8 / 256, 256, 0, stream>>>(X, X16, n8);
  lstm_scan<<<256, 256, 0, stream>>>(X16, h1r, h2r, cnt1, cnt2,
                                     Wih0, Whh0, bih0, bhh0,
                                     Wih1, Whh1, bih1, bhh1, out);
}

// Round 4
// 3415.210 us; speedup vs baseline: 2.5930x; 1.0783x over previous
//
#include <hip/hip_runtime.h>

typedef _Float16 f16;
typedef _Float16 f16x8 __attribute__((ext_vector_type(8)));
typedef float    f32x16 __attribute__((ext_vector_type(16)));

#define T_STEPS 512
#define RING    16   // ring depth (power of 2), slots of 128x512 f16

// ---------------- helpers ----------------

__device__ __forceinline__ void gload_lds16(const void* g, void* l) {
  // async global->LDS, 16B per lane; LDS dest = base + lane*16 (linear)
  __builtin_amdgcn_global_load_lds((const __attribute__((address_space(1))) void*)g,
                                   (__attribute__((address_space(3))) void*)l,
                                   16, 0, 0);
}

__device__ __forceinline__ float sigm(float x) { return 1.0f / (1.0f + __expf(-x)); }
__device__ __forceinline__ float tanh_f(float x) { return 2.0f / (1.0f + __expf(-2.0f * x)) - 1.0f; }

// wave0 polls 32 per-block flags (one LIC line); lane l checks flags[l&31].
// Plain stores by producers (no RMW serialization); monotonic values = t+1.
__device__ __forceinline__ bool spin_flags(const int* f, int target) {
  const int l = threadIdx.x & 31;
  int it = 0;
  while (true) {
    int v = __hip_atomic_load(f + l, __ATOMIC_RELAXED, __HIP_MEMORY_SCOPE_AGENT);
    if (__all(v >= target)) return true;
    __builtin_amdgcn_s_sleep(1);
    if (++it > (1 << 20)) return false;   // safety valve
  }
}

// ---------------- fp32 -> fp16 convert (input_seq) ----------------

__global__ void cvt_kernel(const float* __restrict__ in, f16* __restrict__ out, int n8) {
  int i = blockIdx.x * blockDim.x + threadIdx.x;
  if (i >= n8) return;
  const float4* p = (const float4*)in + (size_t)i * 2;
  float4 a = p[0], b = p[1];
  f16x8 v = {(f16)a.x, (f16)a.y, (f16)a.z, (f16)a.w,
             (f16)b.x, (f16)b.y, (f16)b.z, (f16)b.w};
  *((f16x8*)out + i) = v;
}

// ---------------- persistent 2-layer LSTM scan ----------------
//
// 256 blocks x 256 threads, 1 block/CU (84.7KB LDS forces this -> co-resident).
// bid: xcd=bid&7 -> layer=xcd&1, batch-group g=xcd>>1 (32 rows each); j=bid>>3
// Block (layer,g,j) owns h cols [16j,16j+16) i.e. gate cols q*512+16j.. for q=0..3.
// Wave w: n-tile nt=w&1 (nt0: i,f; nt1: g,o), K-half kh=w>>1. Weights stay in
// VGPRs (32x f16x8 per wave) for the whole scan.
//
// Per step: [pre-spin: X staged by all waves (L0)] -> wave0 spins on flag
// arrays (32 plain-stored words, one line, __all over 32 lanes), acquire
// fence (inv only), issues h staging (L1: h1 issued between the two spins to
// hide its LIC latency under the h2 spin) -> barrier -> MFMA (B from regs)
// -> both K-halves write P[kh][nt] -> barrier -> epilogue sums halves +
// bias, cell update, packed 4B bypass store to LIC -> barrier (vmcnt drain)
// -> tid0 plain-stores its flag = t+1. 3 barriers/step, zero RMWs.

__launch_bounds__(256, 1)
__global__ void lstm_scan(const f16* __restrict__ X16,
                          f16* __restrict__ h1ring, f16* __restrict__ h2ring,
                          int* __restrict__ flags1, int* __restrict__ flags2,
                          const float* __restrict__ Wih0, const float* __restrict__ Whh0,
                          const float* __restrict__ bih0, const float* __restrict__ bhh0,
                          const float* __restrict__ Wih1, const float* __restrict__ Whh1,
                          const float* __restrict__ bih1, const float* __restrict__ bhh1,
                          float* __restrict__ out) {
  __shared__ __align__(16) char A_lds[65536];   // [64 ksteps][kgrp][row][8 f16]
  __shared__ float P[2][2][32][33];             // [kh][nt][row][col] (+1 pad)
  __shared__ float bias_lds[64];
  __shared__ float c_lds[512];                  // cell state, 32 rows x 16 cols

  const int bid  = blockIdx.x;
  const int xcd  = bid & 7;
  const int layer = xcd & 1;
  const int g    = xcd >> 1;
  const int j    = bid >> 3;
  const int tid  = threadIdx.x;
  const int w    = tid >> 6;
  const int lane = tid & 63;
  const int c32  = lane & 31;
  const int kgrp = lane >> 5;
  const int nt   = w & 1;
  const int kh   = w >> 1;

  // ---- load weights into registers (one-time) ----
  const float* Wsrc = layer ? (kh ? Whh1 : Wih1) : (kh ? Whh0 : Wih0);
  const int q    = nt * 2 + (c32 >> 4);
  const int wcol = q * 512 + j * 16 + (c32 & 15);
  f16x8 wreg[32];
  {
    const float* wrow = Wsrc + (size_t)wcol * 512 + kgrp * 8;
#pragma unroll
    for (int s = 0; s < 32; ++s) {
      const float* p = wrow + s * 16;
      float4 a = *(const float4*)p;
      float4 b = *(const float4*)(p + 4);
      f16x8 v = {(f16)a.x, (f16)a.y, (f16)a.z, (f16)a.w,
                 (f16)b.x, (f16)b.y, (f16)b.z, (f16)b.w};
      wreg[s] = v;
    }
  }
  if (tid < 64) {
    int c = tid & 31, n = tid >> 5;
    int qq  = n * 2 + (c >> 4);
    int col = qq * 512 + j * 16 + (c & 15);
    bias_lds[tid] = layer ? (bih1[col] + bhh1[col]) : (bih0[col] + bhh0[col]);
  }
  for (int e = tid; e < 512; e += 256) c_lds[e] = 0.0f;
  __syncthreads();

  const int* f1g = flags1 + g * 32;
  const int* f2g = flags2 + g * 32;
  int* flagOwn = (layer ? flags2 : flags1) + g * 32 + j;
  const int b_stage = g * 32 + c32;   // batch row this lane stages
  const int krow = b_stage * 512 + kgrp * 8;  // common source offset (f16 elems)

  bool alive = true;
  for (int t = 0; t < T_STEPS; ++t) {
    // ---- phase A (L0): X_t -> ksteps 0..31, all 4 waves, 8 issues each ----
    if (layer == 0) {
      const f16* xb = X16 + (size_t)t * 65536 + krow + w * 128;
      char* ld = A_lds + w * 8192;
#pragma unroll
      for (int si = 0; si < 8; ++si) gload_lds16(xb + si * 16, ld + si * 1024);
    }

    // ---- wave0: spin on flags, acquire, issue h staging ----
    if (w == 0) {
      if (layer == 0) {
        if (alive) {
          if (t > 0)     alive &= spin_flags(f1g, t);            // sibling h1[t-1]
          if (t >= RING) alive &= spin_flags(f2g, t - RING + 1); // ring anti-dep
        }
        __builtin_amdgcn_fence(__ATOMIC_ACQUIRE, "agent");       // inv only
        const f16* hb = h1ring + (size_t)(t & (RING - 1)) * 65536 + krow;
#pragma unroll
        for (int ks = 0; ks < 32; ++ks)
          gload_lds16(hb + ks * 16, A_lds + (size_t)(32 + ks) * 1024);
      } else {
        if (alive) alive &= spin_flags(f1g, t + 1);              // h1[t] ready
        __builtin_amdgcn_fence(__ATOMIC_ACQUIRE, "agent");
        const f16* h1b = h1ring + (size_t)((t + 1) & (RING - 1)) * 65536 + krow;
#pragma unroll
        for (int ks = 0; ks < 32; ++ks)
          gload_lds16(h1b + ks * 16, A_lds + (size_t)ks * 1024);
        if (alive && t > 0) alive &= spin_flags(f2g, t);         // sibling h2[t-1]
        __builtin_amdgcn_fence(__ATOMIC_ACQUIRE, "agent");
        const f16* h2b = h2ring + (size_t)(t & (RING - 1)) * 65536 + krow;
#pragma unroll
        for (int ks = 0; ks < 32; ++ks)
          gload_lds16(h2b + ks * 16, A_lds + (size_t)(32 + ks) * 1024);
      }
    }
    __syncthreads();   // wave0's vmcnt(0) covers all staged loads

    // ---- MFMA: acc(32x32) over this wave's K-half, B from registers ----
    f32x16 acc0 = {}, acc1 = {}, acc2 = {}, acc3 = {};
    {
      const char* afb = A_lds + kh * 32768 + kgrp * 512 + c32 * 16;
#pragma unroll
      for (int s = 0; s < 32; s += 4) {
        f16x8 a0 = *(const f16x8*)(afb + (size_t)(s + 0) * 1024);
        f16x8 a1 = *(const f16x8*)(afb + (size_t)(s + 1) * 1024);
        f16x8 a2 = *(const f16x8*)(afb + (size_t)(s + 2) * 1024);
        f16x8 a3 = *(const f16x8*)(afb + (size_t)(s + 3) * 1024);
        acc0 = __builtin_amdgcn_mfma_f32_32x32x16_f16(a0, wreg[s + 0], acc0, 0, 0, 0);
        acc1 = __builtin_amdgcn_mfma_f32_32x32x16_f16(a1, wreg[s + 1], acc1, 0, 0, 0);
        acc2 = __builtin_amdgcn_mfma_f32_32x32x16_f16(a2, wreg[s + 2], acc2, 0, 0, 0);
        acc3 = __builtin_amdgcn_mfma_f32_32x32x16_f16(a3, wreg[s + 3], acc3, 0, 0, 0);
      }
    }
    f32x16 accs = (acc0 + acc1) + (acc2 + acc3);

    // ---- both K-halves write P; C layout col=lane&31, row=(i&3)+8*(i>>2)+4*kgrp ----
#pragma unroll
    for (int i = 0; i < 16; ++i) {
      int row = (i & 3) + 8 * (i >> 2) + 4 * kgrp;
      P[kh][nt][row][c32] = accs[i];
    }
    __syncthreads();

    // ---- epilogue: sum halves + bias, cell update, packed 4B bypass store ----
    {
      f16* ring = layer ? h2ring : h1ring;
      const size_t slot = (size_t)((t + 1) & (RING - 1)) * 65536;
      const int e0 = tid * 2;
      const int r = e0 >> 4, cc = e0 & 15;   // cc even; cols cc, cc+1
      float hv[2];
#pragma unroll
      for (int u = 0; u < 2; ++u) {
        int cu = cc + u;
        float iv = P[0][0][r][cu]      + P[1][0][r][cu]      + bias_lds[cu];
        float fv = P[0][0][r][cu + 16] + P[1][0][r][cu + 16] + bias_lds[cu + 16];
        float gv = P[0][1][r][cu]      + P[1][1][r][cu]      + bias_lds[32 + cu];
        float ov = P[0][1][r][cu + 16] + P[1][1][r][cu + 16] + bias_lds[48 + cu];
        float c  = sigm(fv) * c_lds[e0 + u] + sigm(iv) * tanh_f(gv);
        c_lds[e0 + u] = c;
        hv[u] = sigm(ov) * tanh_f(c);
      }
      union { f16 h2_[2]; int i32; } pk;
      pk.h2_[0] = (f16)hv[0]; pk.h2_[1] = (f16)hv[1];
      int* dst = (int*)(ring + slot + (size_t)(g * 32 + r) * 512 + (j * 16 + cc));
      __hip_atomic_store(dst, pk.i32, __ATOMIC_RELAXED, __HIP_MEMORY_SCOPE_AGENT);
      if (layer && t == T_STEPS - 1) {
        out[(size_t)(g * 32 + r) * 512 + (j * 16 + cc)]     = hv[0];
        out[(size_t)(g * 32 + r) * 512 + (j * 16 + cc) + 1] = hv[1];
      }
    }
    __syncthreads();   // per-wave s_waitcnt vmcnt(0): all h stores ACKed at LIC

    // ---- publish: plain monotonic flag store (no RMW) ----
    if (tid == 0)
      __hip_atomic_store(flagOwn, t + 1, __ATOMIC_RELAXED, __HIP_MEMORY_SCOPE_AGENT);
  }
}

// ---------------- launch ----------------

extern "C" void kernel_launch(void* const* d_in, const int* in_sizes, int n_in,
                              void* d_out, int out_size, void* d_ws, size_t ws_size,
                              hipStream_t stream) {
  const float* X    = (const float*)d_in[0];
  const float* Wih0 = (const float*)d_in[1];
  const float* Whh0 = (const float*)d_in[2];
  const float* bih0 = (const float*)d_in[3];
  const float* bhh0 = (const float*)d_in[4];
  const float* Wih1 = (const float*)d_in[5];
  const float* Whh1 = (const float*)d_in[6];
  const float* bih1 = (const float*)d_in[7];
  const float* bhh1 = (const float*)d_in[8];
  float* out = (float*)d_out;

  char* ws = (char*)d_ws;
  size_t off = 0;
  f16* X16 = (f16*)(ws + off); off += (size_t)512 * 128 * 512 * 2;   // 64 MiB
  f16* h1r = (f16*)(ws + off); off += (size_t)RING * 128 * 512 * 2;  // 2 MiB
  f16* h2r = (f16*)(ws + off); off += (size_t)RING * 128 * 512 * 2;  // 2 MiB
  int* flags1 = (int*)(ws + off); off += 4 * 32 * 4;
  int* flags2 = (int*)(ws + off); off += 4 * 32 * 4;
  if (ws_size < off) return;  // insufficient workspace: fail visibly

  // zero flags and ring slot 0 (h[-1] = 0); d_ws is poisoned each call
  hipMemsetAsync(flags1, 0, 4 * 32 * 4 * 2, stream);  // flags1+flags2 contiguous
  hipMemsetAsync(h1r, 0, (size_t)128 * 512 * 2, stream);
  hipMemsetAsync(h2r, 0, (size_t)128 * 512 * 2, stream);

  int n8 = (512 * 128 * 512) / 8;
  cvt_kernel<<<n8 / 256, 256, 0, stream>>>(X, X16, n8);
  lstm_scan<<<256, 256, 0, stream>>>(X16, h1r, h2r, flags1, flags2,
                                     Wih0, Whh0, bih0, bhh0,
                                     Wih1, Whh1, bih1, bhh1, out);
}